// Round 4
// baseline (268.615 us; speedup 1.0000x reference)
//
#include <hip/hip_runtime.h>

// Problem constants (fixed by setup_inputs)
#define DD 160
#define HH 192
#define WW 160
constexpr int DHW = DD * HH * WW;

// Output tile per block (z,y,x) and staged halo region.
// Halo sized so P(sample outside region) ~0.8% (disp ~ N(0,2) per axis);
// those lanes take the exact global-gather fallback path.
#define TZ 8
#define TY 16
#define TX 16
#define HZ 6
#define HY 5
#define HX 5
#define RZ (TZ + 2*HZ + 1)   // 21
#define RY (TY + 2*HY + 1)   // 27
#define RX (TX + 2*HX + 1)   // 27
constexpr int RYX = RY * RX;  // 729
constexpr int RE  = RZ * RYX; // 15309 floats = 61,236 B  (< 64 KB/WG; 2 blocks/CU)

#define NBX (WW / TX)   // 10
#define NBY (HH / TY)   // 12
#define NBZ (DD / TZ)   // 20

typedef float vfloat4 __attribute__((ext_vector_type(4)));
typedef float vfloat2 __attribute__((ext_vector_type(2)));

// 8-byte pair load, 4B-alignment-safe (backend emits dwordx2).
__device__ __forceinline__ vfloat2 load_pair(const float* __restrict__ p) {
    vfloat2 r;
    __builtin_memcpy(&r, p, 8);
    return r;
}

__global__ __launch_bounds__(512) void st_fused_kernel(
    const float* __restrict__ src,    // [1,1,D,H,W]
    const float* __restrict__ flow1,  // [1,3,D,H,W]
    const float* __restrict__ flow2,  // [1,3,D,H,W]
    const float* __restrict__ prf,    // scalar range_flow
    float* __restrict__ out)          // [DHW deform | 3*DHW out_flow]
{
    __shared__ float sm[RE];

    // XCD-aware bijective swizzle: 2400 blocks = 8 XCDs x 300. Each XCD owns
    // a contiguous z-slab; its staging reads hit a ~2.5 MB L2-resident slab.
    int bid   = (int)blockIdx.x;
    int chunk = (int)gridDim.x >> 3;          // 300 (grid divisible by 8)
    int swz   = (bid & 7) * chunk + (bid >> 3);

    int bx = swz % NBX;
    int by = (swz / NBX) % NBY;
    int bz = swz / (NBX * NBY);

    int t  = (int)threadIdx.x;                 // 0..511
    int xg = t & 3;
    int lyt = (t >> 2) & 15;
    int lzt = t >> 6;

    int xb = bx * TX + xg * 4;                 // 4 consecutive x-voxels
    int y  = by * TY + lyt;
    int z  = bz * TZ + lzt;
    int idx0 = (z * HH + y) * WW + xb;

    const float rf = prf[0];

    // flow2 loads early (NT, streamed once) so they land under the staging.
    const vfloat4 f2zv = __builtin_nontemporal_load((const vfloat4*)(flow2 + idx0));
    const vfloat4 f2yv = __builtin_nontemporal_load((const vfloat4*)(flow2 + idx0 + DHW));
    const vfloat4 f2xv = __builtin_nontemporal_load((const vfloat4*)(flow2 + idx0 + 2 * DHW));

    // ---- stage src tile+halo into LDS (coalesced; coords clamped into the
    // volume — OOB corners get zero WEIGHT so clamped values are never used).
    int gz0 = bz * TZ - HZ;
    int gy0 = by * TY - HY;
    int gx0 = bx * TX - HX;
    for (int i = t; i < RE; i += 512) {
        int rz  = i / RYX;
        int rem = i - rz * RYX;
        int ry  = rem / RX;
        int rx  = rem - ry * RX;
        int gz = min(max(gz0 + rz, 0), DD - 1);
        int gy = min(max(gy0 + ry, 0), HH - 1);
        int gx = min(max(gx0 + rx, 0), WW - 1);
        sm[i] = src[(gz * HH + gy) * WW + gx];
    }
    __syncthreads();

    // ---- phase 1: first grid_sample (flow1 at grid2 treated as NORMALIZED
    // coords) — in-range only in a tiny corner slab; branch rare/uniform.
    float fwz[4], fwy[4], fwx[4];
    #pragma unroll
    for (int j = 0; j < 4; ++j) {
        fwz[j] = 0.0f; fwy[j] = 0.0f; fwx[j] = 0.0f;
        int x = xb + j;
        float g2z = (float)z + f2zv[j] * rf;
        float g2y = (float)y + f2yv[j] * rf;
        float g2x = (float)x + f2xv[j] * rf;
        float iz = ((g2z + 1.0f) * (float)DD - 1.0f) * 0.5f;
        float iy = ((g2y + 1.0f) * (float)HH - 1.0f) * 0.5f;
        float ix = ((g2x + 1.0f) * (float)WW - 1.0f) * 0.5f;
        if (ix > -1.0f && ix < (float)WW &&
            iy > -1.0f && iy < (float)HH &&
            iz > -1.0f && iz < (float)DD) {
            float zf = floorf(iz), yf = floorf(iy), xf = floorf(ix);
            int z0 = (int)zf, y0 = (int)yf, x0 = (int)xf;
            float tz = iz - zf, ty = iy - yf, tx = ix - xf;
            #pragma unroll
            for (int dz = 0; dz < 2; ++dz) {
                int zc = z0 + dz;
                if (zc < 0 || zc >= DD) continue;
                float wzc = dz ? tz : 1.0f - tz;
                #pragma unroll
                for (int dy = 0; dy < 2; ++dy) {
                    int yc = y0 + dy;
                    if (yc < 0 || yc >= HH) continue;
                    float wzy = wzc * (dy ? ty : 1.0f - ty);
                    #pragma unroll
                    for (int dx = 0; dx < 2; ++dx) {
                        int xc = x0 + dx;
                        if (xc < 0 || xc >= WW) continue;
                        float w = wzy * (dx ? tx : 1.0f - tx);
                        int off = (zc * HH + yc) * WW + xc;
                        fwz[j] += w * flow1[off];
                        fwy[j] += w * flow1[off + DHW];
                        fwx[j] += w * flow1[off + 2 * DHW];
                    }
                }
            }
        }
    }

    // ---- phase 2: second grid_sample of src — LDS fast path + rare global
    // fallback for out-of-halo displacements.
    vfloat4 sval, vofz, vofy, vofx;
    #pragma unroll
    for (int j = 0; j < 4; ++j) {
        int x = xb + j;
        float ofz = fwz[j] + f2zv[j];
        float ofy = fwy[j] + f2yv[j];
        float ofx = fwx[j] + f2xv[j];
        vofz[j] = ofz; vofy[j] = ofy; vofx[j] = ofx;

        float nz = (float)z + ofz * rf;
        float ny = (float)y + ofy * rf;
        float nx = (float)x + ofx * rf;
        float cz = 2.0f * (nz / (float)(DD - 1) - 0.5f);
        float cy = 2.0f * (ny / (float)(HH - 1) - 0.5f);
        float cx = 2.0f * (nx / (float)(WW - 1) - 0.5f);
        float sz2 = ((cz + 1.0f) * (float)DD - 1.0f) * 0.5f;
        float sy2 = ((cy + 1.0f) * (float)HH - 1.0f) * 0.5f;
        float sx2 = ((cx + 1.0f) * (float)WW - 1.0f) * 0.5f;

        float zf = floorf(sz2), yf = floorf(sy2), xf = floorf(sx2);
        int z0 = (int)zf, y0 = (int)yf, x0 = (int)xf;
        float tz = sz2 - zf, ty = sy2 - yf, tx = sx2 - xf;

        float wz0 = 1.0f - tz, wz1 = tz;
        float wy0 = 1.0f - ty, wy1 = ty;
        float wx0 = 1.0f - tx, wx1 = tx;
        if (z0 < 0     || z0 >= DD)     wz0 = 0.0f;
        if (z0 + 1 < 0 || z0 + 1 >= DD) wz1 = 0.0f;
        if (y0 < 0     || y0 >= HH)     wy0 = 0.0f;
        if (y0 + 1 < 0 || y0 + 1 >= HH) wy1 = 0.0f;
        if (x0 < 0     || x0 >= WW)     wx0 = 0.0f;
        if (x0 + 1 < 0 || x0 + 1 >= WW) wx1 = 0.0f;

        int lxi = x0 - gx0, lyi = y0 - gy0, lzi = z0 - gz0;
        bool inreg = ((unsigned)lxi <= (unsigned)(RX - 2)) &&
                     ((unsigned)lyi <= (unsigned)(RY - 2)) &&
                     ((unsigned)lzi <= (unsigned)(RZ - 2));

        float acc;
        if (inreg) {
            // LDS gather: 4-byte granular — no cache-line waste, white-noise
            // banks ≈ mild conflict cost only.
            int b = lzi * RYX + lyi * RX + lxi;
            float r00 = fmaf(wx0, sm[b],             wx1 * sm[b + 1]);
            float r01 = fmaf(wx0, sm[b + RX],        wx1 * sm[b + RX + 1]);
            float r10 = fmaf(wx0, sm[b + RYX],       wx1 * sm[b + RYX + 1]);
            float r11 = fmaf(wx0, sm[b + RYX + RX],  wx1 * sm[b + RYX + RX + 1]);
            acc = wz0 * fmaf(wy0, r00, wy1 * r01)
                + wz1 * fmaf(wy0, r10, wy1 * r11);
        } else {
            // exact R2 global path (clamped pair loads, clamp folded into
            // pair weights). Rare: ~0.8% of voxels.
            int zi0 = min(max(z0, 0), DD - 1), zi1 = min(max(z0 + 1, 0), DD - 1);
            int yi0 = min(max(y0, 0), HH - 1), yi1 = min(max(y0 + 1, 0), HH - 1);
            bool lo = (x0 < 0), hi = (x0 > WW - 2);
            int xbase = min(max(x0, 0), WW - 2);
            float wxa = lo ? wx1 : (hi ? 0.0f : wx0);
            float wxb = hi ? wx0 : (lo ? 0.0f : wx1);
            vfloat2 p00 = load_pair(src + (zi0 * HH + yi0) * WW + xbase);
            vfloat2 p01 = load_pair(src + (zi0 * HH + yi1) * WW + xbase);
            vfloat2 p10 = load_pair(src + (zi1 * HH + yi0) * WW + xbase);
            vfloat2 p11 = load_pair(src + (zi1 * HH + yi1) * WW + xbase);
            float r00 = fmaf(wxa, p00.x, wxb * p00.y);
            float r01 = fmaf(wxa, p01.x, wxb * p01.y);
            float r10 = fmaf(wxa, p10.x, wxb * p10.y);
            float r11 = fmaf(wxa, p11.x, wxb * p11.y);
            acc = wz0 * fmaf(wy0, r00, wy1 * r01)
                + wz1 * fmaf(wy0, r10, wy1 * r11);
        }
        sval[j] = acc;
    }

    // outputs: (deform [DHW], out_flow [3*DHW]); NT stores — never re-read.
    __builtin_nontemporal_store(sval, (vfloat4*)(out + idx0));
    __builtin_nontemporal_store(vofz, (vfloat4*)(out + DHW + idx0));
    __builtin_nontemporal_store(vofy, (vfloat4*)(out + 2 * DHW + idx0));
    __builtin_nontemporal_store(vofx, (vfloat4*)(out + 3 * DHW + idx0));
}

extern "C" void kernel_launch(void* const* d_in, const int* in_sizes, int n_in,
                              void* d_out, int out_size, void* d_ws, size_t ws_size,
                              hipStream_t stream) {
    const float* src   = (const float*)d_in[0];
    const float* flow1 = (const float*)d_in[1];
    const float* flow2 = (const float*)d_in[2];
    // d_in[3] is the meshgrid `grid` — deterministic, derived analytically.
    const float* prf   = (const float*)d_in[4];
    float* out = (float*)d_out;

    int blocks = NBX * NBY * NBZ;   // 2400, divisible by 8
    st_fused_kernel<<<blocks, 512, 0, stream>>>(src, flow1, flow2, prf, out);
}

// Round 5
// 256.043 us; speedup vs baseline: 1.0491x; 1.0491x over previous
//
#include <hip/hip_runtime.h>

// Problem constants (fixed by setup_inputs)
#define DD 160
#define HH 192
#define WW 160
constexpr int DHW = DD * HH * WW;

typedef float vfloat4 __attribute__((ext_vector_type(4)));  // native vector for NT builtins
typedef float vfloat2 __attribute__((ext_vector_type(2)));

// 8-byte pair load, 4B-alignment-safe (backend emits global_load_dwordx2).
__device__ __forceinline__ vfloat2 load_pair(const float* __restrict__ p) {
    vfloat2 r;
    __builtin_memcpy(&r, p, 8);
    return r;
}

// __launch_bounds__(256, 4): 4 waves/EU min -> 128-VGPR budget. The POINT of
// this kernel is to keep all 16 scattered pair-gathers in flight at once
// (~48 VGPRs of loads+offsets on top of ~60 live state). With the default
// occupancy target the compiler allocated 48 VGPRs and chunked the batch
// into ~4-load groups, serializing 4x the L2/L3 latency per wave. Measured
// residency is ~14.6 waves/CU, so capping at 16 waves/CU loses nothing.
__global__ __launch_bounds__(256, 4) void st_fused_kernel(
    const float* __restrict__ src,    // [1,1,D,H,W]
    const float* __restrict__ flow1,  // [1,3,D,H,W]
    const float* __restrict__ flow2,  // [1,3,D,H,W]
    const float* __restrict__ prf,    // scalar range_flow
    float* __restrict__ out)          // [DHW deform | 3*DHW out_flow]
{
    // XCD-aware bijective swizzle (4800 = 8 * 600): keeps each XCD's src
    // gather footprint (~2.5 MB slab) inside its 4 MiB L2 (halved FETCH in R1).
    int bid = (int)blockIdx.x;
    int nb  = (int)gridDim.x;
    int swz = bid;
    if ((nb & 7) == 0) {
        int chunk = nb >> 3;
        swz = (bid & 7) * chunk + (bid >> 3);
    }
    int tid  = swz * 256 + (int)threadIdx.x;
    int idx0 = tid * 4;                   // 4 consecutive x-voxels per thread
    if (idx0 >= DHW) return;              // DHW % 1024 == 0

    const float rf = prf[0];

    int xb = idx0 % WW;                   // group never crosses a row (WW%4==0)
    int t  = idx0 / WW;
    int y  = t % HH;
    int z  = t / HH;

    // flow2 streamed once -> nontemporal, don't evict the hot src slab.
    const vfloat4 f2zv = __builtin_nontemporal_load((const vfloat4*)(flow2 + idx0));
    const vfloat4 f2yv = __builtin_nontemporal_load((const vfloat4*)(flow2 + idx0 + DHW));
    const vfloat4 f2xv = __builtin_nontemporal_load((const vfloat4*)(flow2 + idx0 + 2 * DHW));

    // ---- phase 1: first grid_sample (flow1 at grid2 treated as NORMALIZED
    // coords) — in-range only in a tiny corner slab; branch rare & uniform.
    float fwz[4], fwy[4], fwx[4];
    #pragma unroll
    for (int j = 0; j < 4; ++j) {
        fwz[j] = 0.0f; fwy[j] = 0.0f; fwx[j] = 0.0f;
        int x = xb + j;
        float g2z = (float)z + f2zv[j] * rf;
        float g2y = (float)y + f2yv[j] * rf;
        float g2x = (float)x + f2xv[j] * rf;
        float iz = ((g2z + 1.0f) * (float)DD - 1.0f) * 0.5f;
        float iy = ((g2y + 1.0f) * (float)HH - 1.0f) * 0.5f;
        float ix = ((g2x + 1.0f) * (float)WW - 1.0f) * 0.5f;
        if (ix > -1.0f && ix < (float)WW &&
            iy > -1.0f && iy < (float)HH &&
            iz > -1.0f && iz < (float)DD) {
            float zf = floorf(iz), yf = floorf(iy), xf = floorf(ix);
            int z0 = (int)zf, y0 = (int)yf, x0 = (int)xf;
            float tz = iz - zf, ty = iy - yf, tx = ix - xf;
            #pragma unroll
            for (int dz = 0; dz < 2; ++dz) {
                int zc = z0 + dz;
                if (zc < 0 || zc >= DD) continue;
                float wzc = dz ? tz : 1.0f - tz;
                #pragma unroll
                for (int dy = 0; dy < 2; ++dy) {
                    int yc = y0 + dy;
                    if (yc < 0 || yc >= HH) continue;
                    float wzy = wzc * (dy ? ty : 1.0f - ty);
                    #pragma unroll
                    for (int dx = 0; dx < 2; ++dx) {
                        int xc = x0 + dx;
                        if (xc < 0 || xc >= WW) continue;
                        float w = wzy * (dx ? tx : 1.0f - tx);
                        int off = (zc * HH + yc) * WW + xc;
                        fwz[j] += w * flow1[off];
                        fwy[j] += w * flow1[off + DHW];
                        fwx[j] += w * flow1[off + 2 * DHW];
                    }
                }
            }
        }
    }

    // ---- phase 2: addressing + weights for the second grid_sample.
    // x-corner pair folded into one 8B load; clamp folded into pair weights.
    vfloat4 vofz, vofy, vofx;
    float wzw[4][2], wyw[4][2];
    float wxa[4], wxb[4];
    int   off[4][2][2];                   // float index of pair per (dz,dy)

    #pragma unroll
    for (int j = 0; j < 4; ++j) {
        int x = xb + j;
        float ofz = fwz[j] + f2zv[j];
        float ofy = fwy[j] + f2yv[j];
        float ofx = fwx[j] + f2xv[j];
        vofz[j] = ofz; vofy[j] = ofy; vofx[j] = ofx;

        float nz = (float)z + ofz * rf;
        float ny = (float)y + ofy * rf;
        float nx = (float)x + ofx * rf;
        float cz = 2.0f * (nz / (float)(DD - 1) - 0.5f);
        float cy = 2.0f * (ny / (float)(HH - 1) - 0.5f);
        float cx = 2.0f * (nx / (float)(WW - 1) - 0.5f);
        float sz2 = ((cz + 1.0f) * (float)DD - 1.0f) * 0.5f;
        float sy2 = ((cy + 1.0f) * (float)HH - 1.0f) * 0.5f;
        float sx2 = ((cx + 1.0f) * (float)WW - 1.0f) * 0.5f;

        float zf = floorf(sz2), yf = floorf(sy2), xf = floorf(sx2);
        int z0 = (int)zf, y0 = (int)yf, x0 = (int)xf;
        float tz = sz2 - zf, ty = sy2 - yf, tx = sx2 - xf;

        float wzp[2] = {1.0f - tz, tz};
        float wyp[2] = {1.0f - ty, ty};
        int zi[2], yi[2];
        #pragma unroll
        for (int d = 0; d < 2; ++d) {
            int zc = z0 + d, yc = y0 + d;
            if (zc < 0 || zc >= DD) wzp[d] = 0.0f;
            if (yc < 0 || yc >= HH) wyp[d] = 0.0f;
            zi[d] = min(max(zc, 0), DD - 1);
            yi[d] = min(max(yc, 0), HH - 1);
        }
        wzw[j][0] = wzp[0]; wzw[j][1] = wzp[1];
        wyw[j][0] = wyp[0]; wyw[j][1] = wyp[1];

        float wx0 = 1.0f - tx, wx1 = tx;
        if (x0 < 0 || x0 >= WW)          wx0 = 0.0f;
        if (x0 + 1 < 0 || x0 + 1 >= WW)  wx1 = 0.0f;
        bool lo = (x0 < 0);
        bool hi = (x0 > WW - 2);
        int xbase = min(max(x0, 0), WW - 2);
        wxa[j] = lo ? wx1 : (hi ? 0.0f : wx0);
        wxb[j] = hi ? wx0 : (lo ? 0.0f : wx1);

        #pragma unroll
        for (int dz = 0; dz < 2; ++dz)
            #pragma unroll
            for (int dy = 0; dy < 2; ++dy)
                off[j][dz][dy] = (zi[dz] * HH + yi[dy]) * WW + xbase;
    }

    // out_flow stores issued BEFORE the gather batch: they depend only on
    // phase-1 results, retire 12 VGPRs early, and overlap the gather latency.
    __builtin_nontemporal_store(vofz, (vfloat4*)(out + DHW + idx0));
    __builtin_nontemporal_store(vofy, (vfloat4*)(out + 2 * DHW + idx0));
    __builtin_nontemporal_store(vofx, (vfloat4*)(out + 3 * DHW + idx0));

    // ---- phase 3: ALL 16 independent pair-gathers issued back-to-back.
    // With the 128-VGPR budget the whole batch (16 offsets + 32 result regs)
    // stays in flight -> one round of L2/L3 latency per wave, not four.
    vfloat2 v[4][4];
    #pragma unroll
    for (int j = 0; j < 4; ++j)
        #pragma unroll
        for (int dz = 0; dz < 2; ++dz)
            #pragma unroll
            for (int dy = 0; dy < 2; ++dy)
                v[j][dz * 2 + dy] = load_pair(src + off[j][dz][dy]);

    // ---- phase 4: combine + store.
    vfloat4 sval;
    #pragma unroll
    for (int j = 0; j < 4; ++j) {
        float acc = 0.0f;
        #pragma unroll
        for (int dz = 0; dz < 2; ++dz)
            #pragma unroll
            for (int dy = 0; dy < 2; ++dy) {
                float wzy = wzw[j][dz] * wyw[j][dy];
                vfloat2 p = v[j][dz * 2 + dy];
                acc = fmaf(wzy, fmaf(wxa[j], p.x, wxb[j] * p.y), acc);
            }
        sval[j] = acc;
    }
    __builtin_nontemporal_store(sval, (vfloat4*)(out + idx0));
}

extern "C" void kernel_launch(void* const* d_in, const int* in_sizes, int n_in,
                              void* d_out, int out_size, void* d_ws, size_t ws_size,
                              hipStream_t stream) {
    const float* src   = (const float*)d_in[0];
    const float* flow1 = (const float*)d_in[1];
    const float* flow2 = (const float*)d_in[2];
    // d_in[3] is the meshgrid `grid` — deterministic, derived analytically.
    const float* prf   = (const float*)d_in[4];
    float* out = (float*)d_out;

    int threads_total = DHW / 4;
    int blocks = (threads_total + 255) / 256;   // 4800, divisible by 8
    st_fused_kernel<<<blocks, 256, 0, stream>>>(src, flow1, flow2, prf, out);
}

// Round 6
// 247.711 us; speedup vs baseline: 1.0844x; 1.0336x over previous
//
#include <hip/hip_runtime.h>

// Problem constants (fixed by setup_inputs)
#define DD 160
#define HH 192
#define WW 160
constexpr int DHW = DD * HH * WW;

// 3D block tile: 8z x 8y x 16x = 1024 voxels per 256-thread block.
// Gather hot-core footprint (|dz|<=2): 12*13*22*4B ~ 14 KB -> L1-resident.
// (Previous layout: 1024 consecutive x = 141 KB footprint, L1-thrashing.)
#define NBX (WW / 16)   // 10
#define NBY (HH / 8)    // 24
#define NBZ (DD / 8)    // 20

typedef float vfloat4 __attribute__((ext_vector_type(4)));
typedef float vfloat2 __attribute__((ext_vector_type(2)));

// 8-byte pair load, 4B-alignment-safe (backend emits global_load_dwordx2).
__device__ __forceinline__ vfloat2 load_pair(const float* __restrict__ p) {
    vfloat2 r;
    __builtin_memcpy(&r, p, 8);
    return r;
}

__global__ __launch_bounds__(256) void st_fused_kernel(
    const float* __restrict__ src,    // [1,1,D,H,W]
    const float* __restrict__ flow1,  // [1,3,D,H,W]
    const float* __restrict__ flow2,  // [1,3,D,H,W]
    const float* __restrict__ prf,    // scalar range_flow
    float* __restrict__ out)          // [DHW deform | 3*DHW out_flow]
{
    // XCD-aware bijective swizzle (4800 = 8 * 600): each XCD gets a
    // contiguous chunk = ~20 z-slices -> ~2.5 MB src slab, L2-resident.
    int bid   = (int)blockIdx.x;
    int chunk = (int)gridDim.x >> 3;          // 600
    int swz   = (bid & 7) * chunk + (bid >> 3);

    int bx  = swz % NBX;
    int rem = swz / NBX;
    int by  = rem % NBY;
    int bz  = rem / NBY;

    int t  = (int)threadIdx.x;
    int xg = t & 3;                 // 4 threads across x (4 voxels each)
    int ly = (t >> 2) & 7;
    int lz = t >> 5;

    int xb = bx * 16 + xg * 4;      // 4 consecutive x-voxels per thread
    int y  = by * 8 + ly;
    int z  = bz * 8 + lz;
    int idx0 = (z * HH + y) * WW + xb;

    const float rf = prf[0];

    // flow2 streamed once -> nontemporal, don't evict the hot src slab.
    const vfloat4 f2zv = __builtin_nontemporal_load((const vfloat4*)(flow2 + idx0));
    const vfloat4 f2yv = __builtin_nontemporal_load((const vfloat4*)(flow2 + idx0 + DHW));
    const vfloat4 f2xv = __builtin_nontemporal_load((const vfloat4*)(flow2 + idx0 + 2 * DHW));

    // ---- phase 1: first grid_sample (flow1 at grid2 treated as NORMALIZED
    // coords) — in-range only in a tiny corner slab; branch rare & uniform.
    float fwz[4], fwy[4], fwx[4];
    #pragma unroll
    for (int j = 0; j < 4; ++j) {
        fwz[j] = 0.0f; fwy[j] = 0.0f; fwx[j] = 0.0f;
        int x = xb + j;
        float g2z = (float)z + f2zv[j] * rf;
        float g2y = (float)y + f2yv[j] * rf;
        float g2x = (float)x + f2xv[j] * rf;
        float iz = ((g2z + 1.0f) * (float)DD - 1.0f) * 0.5f;
        float iy = ((g2y + 1.0f) * (float)HH - 1.0f) * 0.5f;
        float ix = ((g2x + 1.0f) * (float)WW - 1.0f) * 0.5f;
        if (ix > -1.0f && ix < (float)WW &&
            iy > -1.0f && iy < (float)HH &&
            iz > -1.0f && iz < (float)DD) {
            float zf = floorf(iz), yf = floorf(iy), xf = floorf(ix);
            int z0 = (int)zf, y0 = (int)yf, x0 = (int)xf;
            float tz = iz - zf, ty = iy - yf, tx = ix - xf;
            #pragma unroll
            for (int dz = 0; dz < 2; ++dz) {
                int zc = z0 + dz;
                if (zc < 0 || zc >= DD) continue;
                float wzc = dz ? tz : 1.0f - tz;
                #pragma unroll
                for (int dy = 0; dy < 2; ++dy) {
                    int yc = y0 + dy;
                    if (yc < 0 || yc >= HH) continue;
                    float wzy = wzc * (dy ? ty : 1.0f - ty);
                    #pragma unroll
                    for (int dx = 0; dx < 2; ++dx) {
                        int xc = x0 + dx;
                        if (xc < 0 || xc >= WW) continue;
                        float w = wzy * (dx ? tx : 1.0f - tx);
                        int off = (zc * HH + yc) * WW + xc;
                        fwz[j] += w * flow1[off];
                        fwy[j] += w * flow1[off + DHW];
                        fwx[j] += w * flow1[off + 2 * DHW];
                    }
                }
            }
        }
    }

    // ---- phase 2: addressing + weights for the second grid_sample.
    // x-corner pair folded into one 8B load; clamp folded into pair weights.
    vfloat4 vofz, vofy, vofx;
    float wzw[4][2], wyw[4][2];
    float wxa[4], wxb[4];
    int   off[4][2][2];                   // float index of pair per (dz,dy)

    #pragma unroll
    for (int j = 0; j < 4; ++j) {
        int x = xb + j;
        float ofz = fwz[j] + f2zv[j];
        float ofy = fwy[j] + f2yv[j];
        float ofx = fwx[j] + f2xv[j];
        vofz[j] = ofz; vofy[j] = ofy; vofx[j] = ofx;

        float nz = (float)z + ofz * rf;
        float ny = (float)y + ofy * rf;
        float nx = (float)x + ofx * rf;
        float cz = 2.0f * (nz / (float)(DD - 1) - 0.5f);
        float cy = 2.0f * (ny / (float)(HH - 1) - 0.5f);
        float cx = 2.0f * (nx / (float)(WW - 1) - 0.5f);
        float sz2 = ((cz + 1.0f) * (float)DD - 1.0f) * 0.5f;
        float sy2 = ((cy + 1.0f) * (float)HH - 1.0f) * 0.5f;
        float sx2 = ((cx + 1.0f) * (float)WW - 1.0f) * 0.5f;

        float zf = floorf(sz2), yf = floorf(sy2), xf = floorf(sx2);
        int z0 = (int)zf, y0 = (int)yf, x0 = (int)xf;
        float tz = sz2 - zf, ty = sy2 - yf, tx = sx2 - xf;

        float wzp[2] = {1.0f - tz, tz};
        float wyp[2] = {1.0f - ty, ty};
        int zi[2], yi[2];
        #pragma unroll
        for (int d = 0; d < 2; ++d) {
            int zc = z0 + d, yc = y0 + d;
            if (zc < 0 || zc >= DD) wzp[d] = 0.0f;
            if (yc < 0 || yc >= HH) wyp[d] = 0.0f;
            zi[d] = min(max(zc, 0), DD - 1);
            yi[d] = min(max(yc, 0), HH - 1);
        }
        wzw[j][0] = wzp[0]; wzw[j][1] = wzp[1];
        wyw[j][0] = wyp[0]; wyw[j][1] = wyp[1];

        float wx0 = 1.0f - tx, wx1 = tx;
        if (x0 < 0 || x0 >= WW)          wx0 = 0.0f;
        if (x0 + 1 < 0 || x0 + 1 >= WW)  wx1 = 0.0f;
        bool lo = (x0 < 0);
        bool hi = (x0 > WW - 2);
        int xbase = min(max(x0, 0), WW - 2);
        wxa[j] = lo ? wx1 : (hi ? 0.0f : wx0);
        wxb[j] = hi ? wx0 : (lo ? 0.0f : wx1);

        #pragma unroll
        for (int dz = 0; dz < 2; ++dz)
            #pragma unroll
            for (int dy = 0; dy < 2; ++dy)
                off[j][dz][dy] = (zi[dz] * HH + yi[dy]) * WW + xbase;
    }

    // ---- phase 3: 16 independent pair-gathers back-to-back. With the 3D
    // tile, most land in the block's ~14 KB L1-resident hot core.
    vfloat2 v[4][4];
    #pragma unroll
    for (int j = 0; j < 4; ++j)
        #pragma unroll
        for (int dz = 0; dz < 2; ++dz)
            #pragma unroll
            for (int dy = 0; dy < 2; ++dy)
                v[j][dz * 2 + dy] = load_pair(src + off[j][dz][dy]);

    // ---- phase 4: combine + store.
    vfloat4 sval;
    #pragma unroll
    for (int j = 0; j < 4; ++j) {
        float acc = 0.0f;
        #pragma unroll
        for (int dz = 0; dz < 2; ++dz)
            #pragma unroll
            for (int dy = 0; dy < 2; ++dy) {
                float wzy = wzw[j][dz] * wyw[j][dy];
                vfloat2 p = v[j][dz * 2 + dy];
                acc = fmaf(wzy, fmaf(wxa[j], p.x, wxb[j] * p.y), acc);
            }
        sval[j] = acc;
    }

    // outputs: (deform [DHW], out_flow [3*DHW]); NT stores — never re-read.
    // Each store instruction covers 4 rows x 256 B contiguous segments —
    // same 64B-line count as a fully-contiguous store, no amplification.
    __builtin_nontemporal_store(sval, (vfloat4*)(out + idx0));
    __builtin_nontemporal_store(vofz, (vfloat4*)(out + DHW + idx0));
    __builtin_nontemporal_store(vofy, (vfloat4*)(out + 2 * DHW + idx0));
    __builtin_nontemporal_store(vofx, (vfloat4*)(out + 3 * DHW + idx0));
}

extern "C" void kernel_launch(void* const* d_in, const int* in_sizes, int n_in,
                              void* d_out, int out_size, void* d_ws, size_t ws_size,
                              hipStream_t stream) {
    const float* src   = (const float*)d_in[0];
    const float* flow1 = (const float*)d_in[1];
    const float* flow2 = (const float*)d_in[2];
    // d_in[3] is the meshgrid `grid` — deterministic, derived analytically.
    const float* prf   = (const float*)d_in[4];
    float* out = (float*)d_out;

    int blocks = NBX * NBY * NBZ;   // 10*24*20 = 4800, divisible by 8
    st_fused_kernel<<<blocks, 256, 0, stream>>>(src, flow1, flow2, prf, out);
}

// Round 7
// 232.023 us; speedup vs baseline: 1.1577x; 1.0676x over previous
//
#include <hip/hip_runtime.h>

// Problem constants (fixed by setup_inputs)
#define DD 160
#define HH 192
#define WW 160
constexpr int DHW = DD * HH * WW;

// 3D block tile: 4z x 8y x 32x = 1024 voxels per 256-thread block.
// - Gather footprint ~43 KB/block (same ballpark as R6's tile -> same L2
//   locality under the XCD swizzle).
// - Store geometry: each wave = 8 x-threads (32 floats = 128 B) x 8 y x 1 z
//   -> every store instruction writes 8 contiguous 128 B segments with
//   128 B-aligned bases (row pitch 640 B = 5 sectors, bx*128 offset).
//   Full HBM sectors, no read-modify-write (R6's 64 B half-sector segments
//   caused WRITE_SIZE +25% and FETCH +13 MB).
#define TXD 32
#define TYD 8
#define TZD 4
#define NBX (WW / TXD)   // 5
#define NBY (HH / TYD)   // 24
#define NBZ (DD / TZD)   // 40

typedef float vfloat4 __attribute__((ext_vector_type(4)));
typedef float vfloat2 __attribute__((ext_vector_type(2)));

// 8-byte pair load, 4B-alignment-safe (backend emits global_load_dwordx2).
__device__ __forceinline__ vfloat2 load_pair(const float* __restrict__ p) {
    vfloat2 r;
    __builtin_memcpy(&r, p, 8);
    return r;
}

__global__ __launch_bounds__(256) void st_fused_kernel(
    const float* __restrict__ src,    // [1,1,D,H,W]
    const float* __restrict__ flow1,  // [1,3,D,H,W]
    const float* __restrict__ flow2,  // [1,3,D,H,W]
    const float* __restrict__ prf,    // scalar range_flow
    float* __restrict__ out)          // [DHW deform | 3*DHW out_flow]
{
    // XCD-aware bijective swizzle (4800 = 8 * 600): each XCD owns bz in a
    // 5-wide band = 20 z-slices -> ~2.5 MB src slab, resident in its 4 MB L2.
    int bid   = (int)blockIdx.x;
    int chunk = (int)gridDim.x >> 3;          // 600
    int swz   = (bid & 7) * chunk + (bid >> 3);

    int bx  = swz % NBX;
    int rem = swz / NBX;
    int by  = rem % NBY;
    int bz  = rem / NBY;

    int t  = (int)threadIdx.x;
    int xg = t & 7;                 // 8 threads across x (4 voxels each)
    int ly = (t >> 3) & 7;
    int lz = t >> 6;

    int xb = bx * TXD + xg * 4;     // 4 consecutive x-voxels per thread
    int y  = by * TYD + ly;
    int z  = bz * TZD + lz;
    int idx0 = (z * HH + y) * WW + xb;

    const float rf = prf[0];

    // flow2 streamed once -> nontemporal, don't evict the hot src slab.
    const vfloat4 f2zv = __builtin_nontemporal_load((const vfloat4*)(flow2 + idx0));
    const vfloat4 f2yv = __builtin_nontemporal_load((const vfloat4*)(flow2 + idx0 + DHW));
    const vfloat4 f2xv = __builtin_nontemporal_load((const vfloat4*)(flow2 + idx0 + 2 * DHW));

    // ---- phase 1: first grid_sample (flow1 at grid2 treated as NORMALIZED
    // coords) — in-range only in a tiny corner slab; branch rare & uniform.
    float fwz[4], fwy[4], fwx[4];
    #pragma unroll
    for (int j = 0; j < 4; ++j) {
        fwz[j] = 0.0f; fwy[j] = 0.0f; fwx[j] = 0.0f;
        int x = xb + j;
        float g2z = (float)z + f2zv[j] * rf;
        float g2y = (float)y + f2yv[j] * rf;
        float g2x = (float)x + f2xv[j] * rf;
        float iz = ((g2z + 1.0f) * (float)DD - 1.0f) * 0.5f;
        float iy = ((g2y + 1.0f) * (float)HH - 1.0f) * 0.5f;
        float ix = ((g2x + 1.0f) * (float)WW - 1.0f) * 0.5f;
        if (ix > -1.0f && ix < (float)WW &&
            iy > -1.0f && iy < (float)HH &&
            iz > -1.0f && iz < (float)DD) {
            float zf = floorf(iz), yf = floorf(iy), xf = floorf(ix);
            int z0 = (int)zf, y0 = (int)yf, x0 = (int)xf;
            float tz = iz - zf, ty = iy - yf, tx = ix - xf;
            #pragma unroll
            for (int dz = 0; dz < 2; ++dz) {
                int zc = z0 + dz;
                if (zc < 0 || zc >= DD) continue;
                float wzc = dz ? tz : 1.0f - tz;
                #pragma unroll
                for (int dy = 0; dy < 2; ++dy) {
                    int yc = y0 + dy;
                    if (yc < 0 || yc >= HH) continue;
                    float wzy = wzc * (dy ? ty : 1.0f - ty);
                    #pragma unroll
                    for (int dx = 0; dx < 2; ++dx) {
                        int xc = x0 + dx;
                        if (xc < 0 || xc >= WW) continue;
                        float w = wzy * (dx ? tx : 1.0f - tx);
                        int off = (zc * HH + yc) * WW + xc;
                        fwz[j] += w * flow1[off];
                        fwy[j] += w * flow1[off + DHW];
                        fwx[j] += w * flow1[off + 2 * DHW];
                    }
                }
            }
        }
    }

    // ---- phase 2: addressing + weights for the second grid_sample.
    // x-corner pair folded into one 8B load; clamp folded into pair weights.
    vfloat4 vofz, vofy, vofx;
    float wzw[4][2], wyw[4][2];
    float wxa[4], wxb[4];
    int   off[4][2][2];                   // float index of pair per (dz,dy)

    #pragma unroll
    for (int j = 0; j < 4; ++j) {
        int x = xb + j;
        float ofz = fwz[j] + f2zv[j];
        float ofy = fwy[j] + f2yv[j];
        float ofx = fwx[j] + f2xv[j];
        vofz[j] = ofz; vofy[j] = ofy; vofx[j] = ofx;

        float nz = (float)z + ofz * rf;
        float ny = (float)y + ofy * rf;
        float nx = (float)x + ofx * rf;
        float cz = 2.0f * (nz / (float)(DD - 1) - 0.5f);
        float cy = 2.0f * (ny / (float)(HH - 1) - 0.5f);
        float cx = 2.0f * (nx / (float)(WW - 1) - 0.5f);
        float sz2 = ((cz + 1.0f) * (float)DD - 1.0f) * 0.5f;
        float sy2 = ((cy + 1.0f) * (float)HH - 1.0f) * 0.5f;
        float sx2 = ((cx + 1.0f) * (float)WW - 1.0f) * 0.5f;

        float zf = floorf(sz2), yf = floorf(sy2), xf = floorf(sx2);
        int z0 = (int)zf, y0 = (int)yf, x0 = (int)xf;
        float tz = sz2 - zf, ty = sy2 - yf, tx = sx2 - xf;

        float wzp[2] = {1.0f - tz, tz};
        float wyp[2] = {1.0f - ty, ty};
        int zi[2], yi[2];
        #pragma unroll
        for (int d = 0; d < 2; ++d) {
            int zc = z0 + d, yc = y0 + d;
            if (zc < 0 || zc >= DD) wzp[d] = 0.0f;
            if (yc < 0 || yc >= HH) wyp[d] = 0.0f;
            zi[d] = min(max(zc, 0), DD - 1);
            yi[d] = min(max(yc, 0), HH - 1);
        }
        wzw[j][0] = wzp[0]; wzw[j][1] = wzp[1];
        wyw[j][0] = wyp[0]; wyw[j][1] = wyp[1];

        float wx0 = 1.0f - tx, wx1 = tx;
        if (x0 < 0 || x0 >= WW)          wx0 = 0.0f;
        if (x0 + 1 < 0 || x0 + 1 >= WW)  wx1 = 0.0f;
        bool lo = (x0 < 0);
        bool hi = (x0 > WW - 2);
        int xbase = min(max(x0, 0), WW - 2);
        wxa[j] = lo ? wx1 : (hi ? 0.0f : wx0);
        wxb[j] = hi ? wx0 : (lo ? 0.0f : wx1);

        #pragma unroll
        for (int dz = 0; dz < 2; ++dz)
            #pragma unroll
            for (int dy = 0; dy < 2; ++dy)
                off[j][dz][dy] = (zi[dz] * HH + yi[dy]) * WW + xbase;
    }

    // ---- phase 3: 16 independent pair-gathers back-to-back.
    vfloat2 v[4][4];
    #pragma unroll
    for (int j = 0; j < 4; ++j)
        #pragma unroll
        for (int dz = 0; dz < 2; ++dz)
            #pragma unroll
            for (int dy = 0; dy < 2; ++dy)
                v[j][dz * 2 + dy] = load_pair(src + off[j][dz][dy]);

    // ---- phase 4: combine + store.
    vfloat4 sval;
    #pragma unroll
    for (int j = 0; j < 4; ++j) {
        float acc = 0.0f;
        #pragma unroll
        for (int dz = 0; dz < 2; ++dz)
            #pragma unroll
            for (int dy = 0; dy < 2; ++dy) {
                float wzy = wzw[j][dz] * wyw[j][dy];
                vfloat2 p = v[j][dz * 2 + dy];
                acc = fmaf(wzy, fmaf(wxa[j], p.x, wxb[j] * p.y), acc);
            }
        sval[j] = acc;
    }

    // outputs: (deform [DHW], out_flow [3*DHW]); NT stores — never re-read.
    // Wave store = 8 x 128 B aligned full sectors: no RMW amplification.
    __builtin_nontemporal_store(sval, (vfloat4*)(out + idx0));
    __builtin_nontemporal_store(vofz, (vfloat4*)(out + DHW + idx0));
    __builtin_nontemporal_store(vofy, (vfloat4*)(out + 2 * DHW + idx0));
    __builtin_nontemporal_store(vofx, (vfloat4*)(out + 3 * DHW + idx0));
}

extern "C" void kernel_launch(void* const* d_in, const int* in_sizes, int n_in,
                              void* d_out, int out_size, void* d_ws, size_t ws_size,
                              hipStream_t stream) {
    const float* src   = (const float*)d_in[0];
    const float* flow1 = (const float*)d_in[1];
    const float* flow2 = (const float*)d_in[2];
    // d_in[3] is the meshgrid `grid` — deterministic, derived analytically.
    const float* prf   = (const float*)d_in[4];
    float* out = (float*)d_out;

    int blocks = NBX * NBY * NBZ;   // 5*24*40 = 4800, divisible by 8
    st_fused_kernel<<<blocks, 256, 0, stream>>>(src, flow1, flow2, prf, out);
}